// Round 9
// baseline (138.707 us; speedup 1.0000x reference)
//
#include <hip/hip_runtime.h>
#include <cstddef>

#define B     4
#define DEC   256
#define ENC   1024
#define HID   512
#define UNITS 128

// proj outputs are EXPONENTIATED: Z = 2^(2*log2e * proj) so the score kernel
// computes tanh via  tanh(q+k) = 1 - 2/(1 + Zq*Zk)  with a single rcp and NO
// exp in the 134M-eval inner loop (exp moved to the 655K-eval proj epilogue).
#define PROJ_SCALE 2.8853900817779268f   // 2 * log2(e)

// ---------------------------------------------------------------------------
// Kernel 1: projections. Block = 8 rows x 128 units; each wave handles a
// 128-wide h-quarter (all 8 rows), partials reduced across waves via LDS.
// X reads are wave-uniform (scalar pipe); W reads lane-coalesced b32 from L2,
// depth-1 software prefetch. Epilogue applies 2^x. q rows -> qbuf row-major;
// k rows -> kbufT [b][c=u/4][e][u%4] so score k-loads are coalesced b128.
// ---------------------------------------------------------------------------
__global__ __launch_bounds__(256) void proj_kernel(
    const float* __restrict__ query, const float* __restrict__ value,
    const float* __restrict__ W1,    const float* __restrict__ W2,
    float* __restrict__ qbuf,        float* __restrict__ kbufT)
{
    __shared__ float part[4][8][UNITS];   // 16 KB

    const int tid  = threadIdx.x;
    const int lane = tid & 63;
    const int wv   = __builtin_amdgcn_readfirstlane(tid >> 6);
    const int row0g = blockIdx.x * 8;
    const bool isQ = row0g < B * DEC;
    const float* X = isQ ? query : value;
    const float* W = isQ ? W1 : W2;
    const int row0 = isQ ? row0g : row0g - B * DEC;
    const int h0   = wv * 128;            // this wave's h-quarter

    float acc0[8], acc1[8];
    #pragma unroll
    for (int r = 0; r < 8; ++r) { acc0[r] = 0.f; acc1[r] = 0.f; }

    const float* Xb = X + (size_t)row0 * HID + h0;
    const float* Wb = W + (size_t)h0 * UNITS;

    // preload W group 0
    float wa[4], wb[4];
    #pragma unroll
    for (int j = 0; j < 4; ++j) {
        wa[j] = Wb[j * UNITS + lane];
        wb[j] = Wb[j * UNITS + 64 + lane];
    }

    for (int h = 0; h < 128; h += 4) {
        // prefetch next W group (clamped; last iteration reloads current)
        const int hp = (h + 4 < 128) ? h + 4 : h;
        float na[4], nb[4];
        #pragma unroll
        for (int j = 0; j < 4; ++j) {
            na[j] = Wb[(hp + j) * UNITS + lane];
            nb[j] = Wb[(hp + j) * UNITS + 64 + lane];
        }
        #pragma unroll
        for (int r = 0; r < 8; ++r) {
            const float4 xv = *(const float4*)(Xb + r * HID + h);  // wave-uniform
            acc0[r] += xv.x*wa[0] + xv.y*wa[1] + xv.z*wa[2] + xv.w*wa[3];
            acc1[r] += xv.x*wb[0] + xv.y*wb[1] + xv.z*wb[2] + xv.w*wb[3];
        }
        #pragma unroll
        for (int j = 0; j < 4; ++j) { wa[j] = na[j]; wb[j] = nb[j]; }
    }

    #pragma unroll
    for (int r = 0; r < 8; ++r) {
        part[wv][r][lane]      = acc0[r];
        part[wv][r][64 + lane] = acc1[r];
    }
    __syncthreads();

    // cross-wave reduce + 2^x epilogue: 1024 outputs, 4 per thread
    #pragma unroll
    for (int k = 0; k < 4; ++k) {
        const int idx = tid + k * 256;
        const int r = idx >> 7, u = idx & (UNITS - 1);
        const float s = PROJ_SCALE *
            ((part[0][r][u] + part[1][r][u]) + (part[2][r][u] + part[3][r][u]));
        const float z = __builtin_amdgcn_exp2f(s);   // Z = 2^(2*log2e*proj)
        const int row = row0 + r;
        if (isQ) {
            qbuf[(size_t)row * UNITS + u] = z;
        } else {
            const int bb = row >> 10, e = row & (ENC - 1);
            const int c = u >> 2, j = u & 3;
            kbufT[((size_t)bb * 32 * ENC + (size_t)c * ENC + e) * 4 + j] = z;
        }
    }
}

// ---------------------------------------------------------------------------
// Kernel 2: scores + masked softmax. DQ=2 dec rows per block, 512 blocks x
// 1024 threads = 2 blocks/CU -> 32 waves/CU (100% occupancy; R8's DQ=4 grid
// was 1 block/CU = 50%, ~40% idle slots). Inner step: 3 VALU / 1 trans:
//   t += scale_u * rcp(fma(Zq, Zk, 1))        (exp hoisted into proj)
// Softmax without max-subtraction (|score| <= sum|scale| ~ 11 — safe range);
// masked lanes contribute exactly 0. kv stream depth-2 prefetched, coalesced
// b128. q/scale reads wave-uniform (scalar pipe). XCD-swizzled: b pinned to
// an XCD pair so kbufT[b] (512 KB) stays in that pair's L2.
// ---------------------------------------------------------------------------
__global__ __launch_bounds__(1024) void score_kernel(
    const float* __restrict__ qbuf, const float* __restrict__ kbufT,
    const int* __restrict__ mask,   const float* __restrict__ scale,
    float* __restrict__ attn_out)
{
    const int bi  = blockIdx.x;                      // 0..511
    const int b   = (bi >> 1) & 3;                   // XCD-pair pinning
    const int dq0 = (((bi >> 3) << 1) | (bi & 1)) * 2;
    const int tid = threadIdx.x;                     // 0..1023 == e

    const int m = mask[b * ENC + tid];               // early, independent load

    // S0 = sum(scale) — uniform scalar loop
    float S0 = 0.f;
    for (int j = 0; j < UNITS; j += 4) {
        const float4 sv = *(const float4*)(scale + j);
        S0 += (sv.x + sv.y) + (sv.z + sv.w);
    }

    const float* q0 = qbuf + (size_t)(b * DEC + dq0) * UNITS;
    const float* kc = kbufT + (size_t)b * 32 * ENC * 4 + (size_t)tid * 4;

    float t0 = 0.f, t1 = 0.f;

    // depth-2 kv pipeline
    float4 kv0 = *(const float4*)(kc + (size_t)0 * ENC * 4);
    float4 kv1 = *(const float4*)(kc + (size_t)1 * ENC * 4);
    for (int i = 0; i < 32; ++i) {
        float4 nkv;
        if (i + 2 < 32) nkv = *(const float4*)(kc + (size_t)(i + 2) * ENC * 4);
        const float4 sv = *(const float4*)(scale + i * 4);              // uniform
        const float4 qa = *(const float4*)(q0 + 0 * UNITS + i * 4);     // uniform
        const float4 qb = *(const float4*)(q0 + 1 * UNITS + i * 4);     // uniform
        const float4 kv = kv0;

        t0 += sv.x * __builtin_amdgcn_rcpf(fmaf(qa.x, kv.x, 1.f));
        t0 += sv.y * __builtin_amdgcn_rcpf(fmaf(qa.y, kv.y, 1.f));
        t0 += sv.z * __builtin_amdgcn_rcpf(fmaf(qa.z, kv.z, 1.f));
        t0 += sv.w * __builtin_amdgcn_rcpf(fmaf(qa.w, kv.w, 1.f));
        t1 += sv.x * __builtin_amdgcn_rcpf(fmaf(qb.x, kv.x, 1.f));
        t1 += sv.y * __builtin_amdgcn_rcpf(fmaf(qb.y, kv.y, 1.f));
        t1 += sv.z * __builtin_amdgcn_rcpf(fmaf(qb.z, kv.z, 1.f));
        t1 += sv.w * __builtin_amdgcn_rcpf(fmaf(qb.w, kv.w, 1.f));

        kv0 = kv1;
        if (i + 2 < 32) kv1 = nkv;
    }

    // unnormalized weights; masked lanes contribute exactly 0
    float wgt[2];
    wgt[0] = m ? __expf(S0 - 2.f * t0) : 0.f;
    wgt[1] = m ? __expf(S0 - 2.f * t1) : 0.f;

    __shared__ float reds[2][16];
    const int lane = tid & 63, wv = tid >> 6;   // 16 waves

    float ls[2] = {wgt[0], wgt[1]};
    #pragma unroll
    for (int off = 32; off > 0; off >>= 1) {
        #pragma unroll
        for (int r = 0; r < 2; ++r)
            ls[r] += __shfl_down(ls[r], off, 64);
    }
    if (lane == 0) {
        #pragma unroll
        for (int r = 0; r < 2; ++r) reds[r][wv] = ls[r];
    }
    __syncthreads();
    #pragma unroll
    for (int r = 0; r < 2; ++r) {
        float g = 0.f;
        #pragma unroll
        for (int w = 0; w < 16; ++w) g += reds[r][w];
        attn_out[(size_t)(b * DEC + dq0 + r) * ENC + tid] =
            wgt[r] * __builtin_amdgcn_rcpf(g);
    }
}

// ---------------------------------------------------------------------------
// Kernel 3: ctx = attn @ value. 512 blocks x 512 threads: 8 dec rows x 128
// h-cols per block. Attention rows staged in LDS; weights fetched as
// same-address ds_read_b128 broadcasts (LDS pipe, co-issues with fma stream).
// Value loads software-pipelined depth-1. 8-way cross-wave reduce via LDS.
// ---------------------------------------------------------------------------
__global__ __launch_bounds__(512) void ctx_kernel(
    const float* __restrict__ attn, const float* __restrict__ value,
    float* __restrict__ ctx)
{
    __shared__ float attnS[8][ENC];     // 32 KB
    __shared__ float part[8][8][128];   // 32 KB

    const int bi   = blockIdx.x;                 // 0..511, XCD-swizzled
    const int b    = (bi >> 1) & 3;              // b pinned to an XCD pair
    const int idx  = ((bi >> 3) << 1) | (bi & 1);
    const int row0 = (idx >> 2) * 8;
    const int h0   = (idx & 3) * 128;
    const int tid  = threadIdx.x;
    const int lane = tid & 63;
    const int wv   = __builtin_amdgcn_readfirstlane(tid >> 6);  // 0..7

    // stage 8 attention rows (coalesced b64: 1024 e / 512 threads = 2 each)
    const float* ab = attn + (size_t)(b * DEC + row0) * ENC;
    #pragma unroll
    for (int r = 0; r < 8; ++r) {
        const float2 v = *(const float2*)(ab + (size_t)r * ENC + tid * 2);
        *(float2*)&attnS[r][tid * 2] = v;
    }
    __syncthreads();

    float acc[8][2];
    #pragma unroll
    for (int r = 0; r < 8; ++r) { acc[r][0] = 0.f; acc[r][1] = 0.f; }

    const float* vb = value + (size_t)b * ENC * HID + h0 + lane * 2;
    const int e0 = wv * 128;

    // preload group 0's value columns
    float2 va[4];
    #pragma unroll
    for (int j = 0; j < 4; ++j)
        va[j] = *(const float2*)(vb + (size_t)(e0 + j) * HID);

    for (int g = 0; g < 32; ++g) {                // 4-e groups
        const int gp = (g + 1 < 32) ? g + 1 : g;  // clamped prefetch
        float2 vn[4];
        #pragma unroll
        for (int j = 0; j < 4; ++j)
            vn[j] = *(const float2*)(vb + (size_t)(e0 + gp * 4 + j) * HID);

        const int eg = e0 + g * 4;
        float4 w4[8];
        #pragma unroll
        for (int r = 0; r < 8; ++r)
            w4[r] = *(const float4*)&attnS[r][eg];   // same-addr broadcast b128

        #pragma unroll
        for (int j = 0; j < 4; ++j) {
            const float2 v2 = va[j];
            #pragma unroll
            for (int r = 0; r < 8; ++r) {
                const float w = ((const float*)&w4[r])[j];
                acc[r][0] += w * v2.x;
                acc[r][1] += w * v2.y;
            }
        }
        #pragma unroll
        for (int j = 0; j < 4; ++j) va[j] = vn[j];
    }

    #pragma unroll
    for (int r = 0; r < 8; ++r)
        *(float2*)&part[wv][r][lane * 2] = make_float2(acc[r][0], acc[r][1]);
    __syncthreads();

    // 8-way cross-wave reduce: 1024 outputs, 2 per thread, stride-1 in h
    #pragma unroll
    for (int k = 0; k < 2; ++k) {
        const int idx2 = tid + k * 512;
        const int r = idx2 >> 7, hh = idx2 & 127;
        float s = 0.f;
        #pragma unroll
        for (int w = 0; w < 8; ++w) s += part[w][r][hh];
        ctx[(size_t)(b * DEC + row0 + r) * HID + h0 + hh] = s;
    }
}

extern "C" void kernel_launch(void* const* d_in, const int* in_sizes, int n_in,
                              void* d_out, int out_size, void* d_ws, size_t ws_size,
                              hipStream_t stream) {
    const float* query = (const float*)d_in[0];
    const float* value = (const float*)d_in[1];
    const int*   mask  = (const int*)  d_in[2];
    const float* W1    = (const float*)d_in[3];
    const float* W2    = (const float*)d_in[4];
    const float* scale = (const float*)d_in[5];

    float* qbuf  = (float*)d_ws;                       // B*DEC*UNITS   = 131072 floats
    float* kbufT = qbuf + (size_t)B * DEC * UNITS;     // B*32*ENC*4    = 524288 floats

    float* ctx_out  = (float*)d_out;                   // B*DEC*HID
    float* attn_out = ctx_out + (size_t)B * DEC * HID; // B*DEC*ENC

    proj_kernel <<<640,  256, 0, stream>>>(query, value, W1, W2, qbuf, kbufT);
    score_kernel<<<512, 1024, 0, stream>>>(qbuf, kbufT, mask, scale, attn_out);
    ctx_kernel  <<<512,  512, 0, stream>>>(attn_out, value, ctx_out);
}

// Round 11
// 130.735 us; speedup vs baseline: 1.0610x; 1.0610x over previous
//
#include <hip/hip_runtime.h>
#include <cstddef>

#define B     4
#define DEC   256
#define ENC   1024
#define HID   512
#define UNITS 128

// proj outputs are EXPONENTIATED: Z = 2^(2*log2e * proj) so the score kernel
// computes tanh via  tanh(q+k) = 1 - 2/(1 + Zq*Zk)  with NO exp in the
// 134M-eval inner loop (exp moved to the 655K-eval proj epilogue).
#define PROJ_SCALE 2.8853900817779268f   // 2 * log2(e)

// ---------------------------------------------------------------------------
// Kernel 1: projections. Block = 8 rows x 128 units; each wave handles a
// 128-wide h-quarter (all 8 rows), partials reduced across waves via LDS.
// X reads are wave-uniform (scalar pipe); W reads lane-coalesced b32 from L2,
// depth-1 software prefetch. Epilogue applies 2^x. q rows -> qbuf row-major;
// k rows -> kbufT [b][c=u/4][e][u%4] so score k-loads are coalesced b128.
// ---------------------------------------------------------------------------
__global__ __launch_bounds__(256) void proj_kernel(
    const float* __restrict__ query, const float* __restrict__ value,
    const float* __restrict__ W1,    const float* __restrict__ W2,
    float* __restrict__ qbuf,        float* __restrict__ kbufT)
{
    __shared__ float part[4][8][UNITS];   // 16 KB

    const int tid  = threadIdx.x;
    const int lane = tid & 63;
    const int wv   = __builtin_amdgcn_readfirstlane(tid >> 6);
    const int row0g = blockIdx.x * 8;
    const bool isQ = row0g < B * DEC;
    const float* X = isQ ? query : value;
    const float* W = isQ ? W1 : W2;
    const int row0 = isQ ? row0g : row0g - B * DEC;
    const int h0   = wv * 128;            // this wave's h-quarter

    float acc0[8], acc1[8];
    #pragma unroll
    for (int r = 0; r < 8; ++r) { acc0[r] = 0.f; acc1[r] = 0.f; }

    const float* Xb = X + (size_t)row0 * HID + h0;
    const float* Wb = W + (size_t)h0 * UNITS;

    // preload W group 0
    float wa[4], wb[4];
    #pragma unroll
    for (int j = 0; j < 4; ++j) {
        wa[j] = Wb[j * UNITS + lane];
        wb[j] = Wb[j * UNITS + 64 + lane];
    }

    for (int h = 0; h < 128; h += 4) {
        // prefetch next W group (clamped; last iteration reloads current)
        const int hp = (h + 4 < 128) ? h + 4 : h;
        float na[4], nb[4];
        #pragma unroll
        for (int j = 0; j < 4; ++j) {
            na[j] = Wb[(hp + j) * UNITS + lane];
            nb[j] = Wb[(hp + j) * UNITS + 64 + lane];
        }
        #pragma unroll
        for (int r = 0; r < 8; ++r) {
            const float4 xv = *(const float4*)(Xb + r * HID + h);  // wave-uniform
            acc0[r] += xv.x*wa[0] + xv.y*wa[1] + xv.z*wa[2] + xv.w*wa[3];
            acc1[r] += xv.x*wb[0] + xv.y*wb[1] + xv.z*wb[2] + xv.w*wb[3];
        }
        #pragma unroll
        for (int j = 0; j < 4; ++j) { wa[j] = na[j]; wb[j] = nb[j]; }
    }

    #pragma unroll
    for (int r = 0; r < 8; ++r) {
        part[wv][r][lane]      = acc0[r];
        part[wv][r][64 + lane] = acc1[r];
    }
    __syncthreads();

    // cross-wave reduce + 2^x epilogue: 1024 outputs, 4 per thread
    #pragma unroll
    for (int k = 0; k < 4; ++k) {
        const int idx = tid + k * 256;
        const int r = idx >> 7, u = idx & (UNITS - 1);
        const float s = PROJ_SCALE *
            ((part[0][r][u] + part[1][r][u]) + (part[2][r][u] + part[3][r][u]));
        const float z = __builtin_amdgcn_exp2f(s);   // Z = 2^(2*log2e*proj)
        const int row = row0 + r;
        if (isQ) {
            qbuf[(size_t)row * UNITS + u] = z;
        } else {
            const int bb = row >> 10, e = row & (ENC - 1);
            const int c = u >> 2, j = u & 3;
            kbufT[((size_t)bb * 32 * ENC + (size_t)c * ENC + e) * 4 + j] = z;
        }
    }
}

// pairwise fused sigmoid-sum: s0/dA + s1/dB with ONE rcp, where
// dA = 1 + q0*k0, dB = 1 + q1*k1  (exact algebra, halves trans-pipe work)
__device__ __forceinline__ float pair_term(float q0, float q1, float k0, float k1,
                                           float s0, float s1) {
    const float dA = fmaf(q0, k0, 1.f);
    const float dB = fmaf(q1, k1, 1.f);
    const float n  = fmaf(s0, dB, s1 * dA);
    return n * __builtin_amdgcn_rcpf(dA * dB);
}

// ---------------------------------------------------------------------------
// Kernel 2: scores + masked softmax. DQ=4 dec rows per block, 256 blocks x
// 1024 threads (R8 grid — best measured). R9 post-mortem: score is
// trans-pipe-bound (v_rcp ~16 cyc/wave); this version halves the rcp count
// via exact pairwise combining:  s0/A0 + s1/A1 = (s0*A1 + s1*A0)/(A0*A1).
// 8 rcp per 16 sigmoids (was 16). Softmax without max-subtraction
// (|score| <= sum|scale| ~ 11 — safe); masked lanes contribute exactly 0.
// q/scale reads wave-uniform (scalar pipe), kv coalesced b128, depth-1
// prefetch. XCD-swizzled: b pinned to an XCD pair (kbufT[b] = 512 KB in L2).
// ---------------------------------------------------------------------------
__global__ __launch_bounds__(1024) void score_kernel(
    const float* __restrict__ qbuf, const float* __restrict__ kbufT,
    const int* __restrict__ mask,   const float* __restrict__ scale,
    float* __restrict__ attn_out)
{
    const int bi  = blockIdx.x;                      // 0..255
    const int b   = (bi >> 1) & 3;                   // XCD-pair pinning
    const int dq0 = (((bi >> 3) << 1) | (bi & 1)) * 4;
    const int tid = threadIdx.x;                     // 0..1023 == e

    const int m = mask[b * ENC + tid];               // early, independent load

    // S0 = sum(scale) — uniform scalar loop
    float S0 = 0.f;
    for (int j = 0; j < UNITS; j += 4) {
        const float4 sv = *(const float4*)(scale + j);
        S0 += (sv.x + sv.y) + (sv.z + sv.w);
    }

    const float* q0 = qbuf + (size_t)(b * DEC + dq0) * UNITS;
    const float* kc = kbufT + (size_t)b * 32 * ENC * 4 + (size_t)tid * 4;

    float t0 = 0.f, t1 = 0.f, t2 = 0.f, t3 = 0.f;

    float4 kv = *(const float4*)kc;                  // depth-1 kv prefetch
    for (int i = 0; i < 32; ++i) {
        float4 nkv;
        if (i + 1 < 32) nkv = *(const float4*)(kc + (size_t)(i + 1) * ENC * 4);
        const float4 sv = *(const float4*)(scale + i * 4);              // uniform
        const float4 qa = *(const float4*)(q0 + 0 * UNITS + i * 4);     // uniform
        const float4 qb = *(const float4*)(q0 + 1 * UNITS + i * 4);
        const float4 qc = *(const float4*)(q0 + 2 * UNITS + i * 4);
        const float4 qd = *(const float4*)(q0 + 3 * UNITS + i * 4);

        t0 += pair_term(qa.x, qa.y, kv.x, kv.y, sv.x, sv.y);
        t0 += pair_term(qa.z, qa.w, kv.z, kv.w, sv.z, sv.w);
        t1 += pair_term(qb.x, qb.y, kv.x, kv.y, sv.x, sv.y);
        t1 += pair_term(qb.z, qb.w, kv.z, kv.w, sv.z, sv.w);
        t2 += pair_term(qc.x, qc.y, kv.x, kv.y, sv.x, sv.y);
        t2 += pair_term(qc.z, qc.w, kv.z, kv.w, sv.z, sv.w);
        t3 += pair_term(qd.x, qd.y, kv.x, kv.y, sv.x, sv.y);
        t3 += pair_term(qd.z, qd.w, kv.z, kv.w, sv.z, sv.w);

        if (i + 1 < 32) kv = nkv;
    }

    // unnormalized weights; masked lanes contribute exactly 0
    float wgt[4];
    wgt[0] = m ? __expf(S0 - 2.f * t0) : 0.f;
    wgt[1] = m ? __expf(S0 - 2.f * t1) : 0.f;
    wgt[2] = m ? __expf(S0 - 2.f * t2) : 0.f;
    wgt[3] = m ? __expf(S0 - 2.f * t3) : 0.f;

    __shared__ float reds[4][16];
    const int lane = tid & 63, wv = tid >> 6;   // 16 waves

    float ls[4] = {wgt[0], wgt[1], wgt[2], wgt[3]};
    #pragma unroll
    for (int off = 32; off > 0; off >>= 1) {
        #pragma unroll
        for (int r = 0; r < 4; ++r)
            ls[r] += __shfl_down(ls[r], off, 64);
    }
    if (lane == 0) {
        #pragma unroll
        for (int r = 0; r < 4; ++r) reds[r][wv] = ls[r];
    }
    __syncthreads();
    #pragma unroll
    for (int r = 0; r < 4; ++r) {
        float g = 0.f;
        #pragma unroll
        for (int w = 0; w < 16; ++w) g += reds[r][w];
        attn_out[(size_t)(b * DEC + dq0 + r) * ENC + tid] =
            wgt[r] * __builtin_amdgcn_rcpf(g);
    }
}

// ---------------------------------------------------------------------------
// Kernel 3: ctx = attn @ value. 512 blocks x 512 threads: 8 dec rows x 128
// h-cols per block. Attention rows staged in LDS; weights fetched as
// same-address ds_read_b128 broadcasts (LDS pipe, co-issues with fma stream).
// Value loads software-pipelined depth-1. 8-way cross-wave reduce via LDS.
// ---------------------------------------------------------------------------
__global__ __launch_bounds__(512) void ctx_kernel(
    const float* __restrict__ attn, const float* __restrict__ value,
    float* __restrict__ ctx)
{
    __shared__ float attnS[8][ENC];     // 32 KB
    __shared__ float part[8][8][128];   // 32 KB

    const int bi   = blockIdx.x;                 // 0..511, XCD-swizzled
    const int b    = (bi >> 1) & 3;              // b pinned to an XCD pair
    const int idx  = ((bi >> 3) << 1) | (bi & 1);
    const int row0 = (idx >> 2) * 8;
    const int h0   = (idx & 3) * 128;
    const int tid  = threadIdx.x;
    const int lane = tid & 63;
    const int wv   = __builtin_amdgcn_readfirstlane(tid >> 6);  // 0..7

    // stage 8 attention rows (coalesced b64: 1024 e / 512 threads = 2 each)
    const float* ab = attn + (size_t)(b * DEC + row0) * ENC;
    #pragma unroll
    for (int r = 0; r < 8; ++r) {
        const float2 v = *(const float2*)(ab + (size_t)r * ENC + tid * 2);
        *(float2*)&attnS[r][tid * 2] = v;
    }
    __syncthreads();

    float acc[8][2];
    #pragma unroll
    for (int r = 0; r < 8; ++r) { acc[r][0] = 0.f; acc[r][1] = 0.f; }

    const float* vb = value + (size_t)b * ENC * HID + h0 + lane * 2;
    const int e0 = wv * 128;

    // preload group 0's value columns
    float2 va[4];
    #pragma unroll
    for (int j = 0; j < 4; ++j)
        va[j] = *(const float2*)(vb + (size_t)(e0 + j) * HID);

    for (int g = 0; g < 32; ++g) {                // 4-e groups
        const int gp = (g + 1 < 32) ? g + 1 : g;  // clamped prefetch
        float2 vn[4];
        #pragma unroll
        for (int j = 0; j < 4; ++j)
            vn[j] = *(const float2*)(vb + (size_t)(e0 + gp * 4 + j) * HID);

        const int eg = e0 + g * 4;
        float4 w4[8];
        #pragma unroll
        for (int r = 0; r < 8; ++r)
            w4[r] = *(const float4*)&attnS[r][eg];   // same-addr broadcast b128

        #pragma unroll
        for (int j = 0; j < 4; ++j) {
            const float2 v2 = va[j];
            #pragma unroll
            for (int r = 0; r < 8; ++r) {
                const float w = ((const float*)&w4[r])[j];
                acc[r][0] += w * v2.x;
                acc[r][1] += w * v2.y;
            }
        }
        #pragma unroll
        for (int j = 0; j < 4; ++j) va[j] = vn[j];
    }

    #pragma unroll
    for (int r = 0; r < 8; ++r)
        *(float2*)&part[wv][r][lane * 2] = make_float2(acc[r][0], acc[r][1]);
    __syncthreads();

    // 8-way cross-wave reduce: 1024 outputs, 2 per thread, stride-1 in h
    #pragma unroll
    for (int k = 0; k < 2; ++k) {
        const int idx2 = tid + k * 512;
        const int r = idx2 >> 7, hh = idx2 & 127;
        float s = 0.f;
        #pragma unroll
        for (int w = 0; w < 8; ++w) s += part[w][r][hh];
        ctx[(size_t)(b * DEC + row0 + r) * HID + h0 + hh] = s;
    }
}

extern "C" void kernel_launch(void* const* d_in, const int* in_sizes, int n_in,
                              void* d_out, int out_size, void* d_ws, size_t ws_size,
                              hipStream_t stream) {
    const float* query = (const float*)d_in[0];
    const float* value = (const float*)d_in[1];
    const int*   mask  = (const int*)  d_in[2];
    const float* W1    = (const float*)d_in[3];
    const float* W2    = (const float*)d_in[4];
    const float* scale = (const float*)d_in[5];

    float* qbuf  = (float*)d_ws;                       // B*DEC*UNITS   = 131072 floats
    float* kbufT = qbuf + (size_t)B * DEC * UNITS;     // B*32*ENC*4    = 524288 floats

    float* ctx_out  = (float*)d_out;                   // B*DEC*HID
    float* attn_out = ctx_out + (size_t)B * DEC * HID; // B*DEC*ENC

    proj_kernel <<<640,  256, 0, stream>>>(query, value, W1, W2, qbuf, kbufT);
    score_kernel<<<256, 1024, 0, stream>>>(qbuf, kbufT, mask, scale, attn_out);
    ctx_kernel  <<<512,  512, 0, stream>>>(attn_out, value, ctx_out);
}